// Round 2
// baseline (1121.283 us; speedup 1.0000x reference)
//
#include <hip/hip_runtime.h>
#include <hip/hip_bf16.h>

typedef __attribute__((ext_vector_type(8))) short short8;
typedef __attribute__((ext_vector_type(4))) float floatx4;

static __device__ __forceinline__ unsigned short f2bf(float f){
  union { float f; unsigned int u; } v; v.f = f;
  return (unsigned short)((v.u + 0x7FFFu + ((v.u >> 16) & 1u)) >> 16);  // RNE
}

// ---------------- old small-GEMM machinery (128-B-element rows = 256 B) ----------------
template<int ROWS>
static __device__ __forceinline__ void stage_tile(char* ldsbase, const float* __restrict__ src,
                                                  int ld, int tid){
  #pragma unroll
  for (int w = 0; w < ROWS/32; ++w){
    int g = w*512 + tid;
    int row = g >> 4, k8 = g & 15;
    const float* p = src + (size_t)row*ld + k8*8;
    floatx4 v0 = *(const floatx4*)p;
    floatx4 v1 = *(const floatx4*)(p+4);
    short8 s;
    s[0] = (short)f2bf(v0[0]); s[1] = (short)f2bf(v0[1]);
    s[2] = (short)f2bf(v0[2]); s[3] = (short)f2bf(v0[3]);
    s[4] = (short)f2bf(v1[0]); s[5] = (short)f2bf(v1[1]);
    s[6] = (short)f2bf(v1[2]); s[7] = (short)f2bf(v1[3]);
    *(short8*)(ldsbase + row*256 + ((k8*16) ^ ((row & 7) << 4))) = s;
  }
}

static __device__ __forceinline__ short8 frag_ld(const char* ldsbase, int row, int kbyte){
  return *(const short8*)(ldsbase + row*256 + (kbyte ^ ((row & 7) << 4)));
}

// MODE 0: out = relu(A@B^T + bias); MODE 1: out = A@B^T. K=512, A [1024][512].
template<int MODE>
__global__ __launch_bounds__(512)
void gemm_plain(const float* __restrict__ Asrc, const float* __restrict__ Bsrc,
                const float* __restrict__ bias, float* __restrict__ out, int out_ld){
  __shared__ char smem[98304];
  char* At = smem;            // [256][128] bf16 swz
  char* Bt = smem + 65536;    // [128][128] bf16 swz
  const int tid  = threadIdx.x;
  const int lane = tid & 63, w = tid >> 6;
  const int wm = w & 3, wn = w >> 2;
  const int bid = blockIdx.x;
  const int t0 = (bid & 3) * 256;
  const int c0 = (bid >> 2) * 128;
  const int rbase = wm*64, cbase = wn*64;

  floatx4 acc[4][4];
  #pragma unroll
  for (int i=0;i<4;++i)
    #pragma unroll
    for (int j=0;j<4;++j) acc[i][j] = floatx4{0.f,0.f,0.f,0.f};

  for (int kb = 0; kb < 4; ++kb){
    __syncthreads();
    stage_tile<256>(At, Asrc + (size_t)t0*512 + kb*128, 512, tid);
    stage_tile<128>(Bt, Bsrc + (size_t)c0*512 + kb*128, 512, tid);
    __syncthreads();
    #pragma unroll
    for (int ks = 0; ks < 4; ++ks){
      const int kbyte = (ks*32 + (lane>>4)*8) * 2;
      short8 af[4], bf[4];
      #pragma unroll
      for (int mi=0; mi<4; ++mi) af[mi] = frag_ld(At, rbase + mi*16 + (lane&15), kbyte);
      #pragma unroll
      for (int ni=0; ni<4; ++ni) bf[ni] = frag_ld(Bt, cbase + ni*16 + (lane&15), kbyte);
      #pragma unroll
      for (int mi=0; mi<4; ++mi)
        #pragma unroll
        for (int ni=0; ni<4; ++ni)
          acc[mi][ni] = __builtin_amdgcn_mfma_f32_16x16x32_bf16(af[mi], bf[ni], acc[mi][ni], 0,0,0);
    }
  }
  #pragma unroll
  for (int mi=0; mi<4; ++mi){
    #pragma unroll
    for (int ni=0; ni<4; ++ni){
      #pragma unroll
      for (int rg=0; rg<4; ++rg){
        int t = t0 + rbase + mi*16 + (lane>>4)*4 + rg;
        int c = c0 + cbase + ni*16 + (lane&15);
        float v = acc[mi][ni][rg];
        if (MODE == 0) { v += bias[c]; v = v > 0.f ? v : 0.f; }
        out[(size_t)t*out_ld + c] = v;
      }
    }
  }
}

// ---------------- pipelined big GEMM (64-elem = 128 B LDS rows) ----------------
static __device__ __forceinline__ short8 frag_ld64(const char* base, int row, int kbyte){
  return *(const short8*)(base + row*128 + (kbyte ^ ((row & 7) << 4)));
}

// C[M=1024][Ncols] (+=) A' @ B^T over K, tile 256x128, BK=64, double-buffered, 1 barrier/step.
// SCALED: A'[t,K] = Rsrc[t*512 + (K>>9)] * Asrc[t*512 + (K&511)]  (on-the-fly einsum A)
// else  : A'[t,K] = Asrc[t*512 + K]  (K < 512)
// B[c,K] = Bsrc[c*Bstride + K]. ATOMIC: atomicAdd into out; else out = acc + bias[c].
template<int SCALED, int ATOMIC>
__global__ __launch_bounds__(512, 2)
void gemm_pipe(const float* __restrict__ Asrc, const float* __restrict__ Rsrc,
               const float* __restrict__ Bsrc, const float* __restrict__ bias,
               float* __restrict__ out, int out_ld, int gridN, int nsteps,
               size_t Bstride){
  __shared__ char smem[98304];   // Abuf[2]: 0..65535 (2x 256x64 bf16 swz), Bbuf[2]: 65536..98303
  const int tid  = threadIdx.x;
  const int lane = tid & 63, w = tid >> 6;
  const int wm = w & 3, wn = w >> 2;          // 8 waves: 4M x 2N, wave tile 64x64
  const int bid = blockIdx.x;
  const int m    = bid & 3;
  const int rest = bid >> 2;
  const int nt   = rest % gridN;
  const int kid  = rest / gridN;
  const int t0 = m * 256, c0 = nt * 128;
  const long K0b = (long)kid * nsteps * 64;

  const int arow = tid >> 1, akh = (tid & 1) * 32;   // A stage: 2 thr/row, 32 elems each
  const int brow = tid >> 2, bkh = (tid & 3) * 16;   // B stage: 4 thr/row, 16 elems each

  const float* aptr_base = Asrc + (size_t)(t0 + arow) * 512 + akh;
  const float* bptr_base = Bsrc + (size_t)(c0 + brow) * Bstride + bkh;

  floatx4 acc[4][4];
  #pragma unroll
  for (int i=0;i<4;++i)
    #pragma unroll
    for (int j=0;j<4;++j) acc[i][j] = floatx4{0.f,0.f,0.f,0.f};

  floatx4 la[8], lb[4];
  float rv = 1.0f;

  auto issue = [&](int s){
    const long K0 = K0b + (long)s * 64;
    const float* ap = aptr_base + (SCALED ? (K0 & 511) : K0);
    #pragma unroll
    for (int i=0;i<8;++i) la[i] = *(const floatx4*)(ap + i*4);
    if (SCALED) rv = Rsrc[(size_t)(t0 + arow)*512 + (K0 >> 9)];
    const float* bp = bptr_base + K0;
    #pragma unroll
    for (int i=0;i<4;++i) lb[i] = *(const floatx4*)(bp + i*4);
  };

  auto write_buf = [&](int buf){
    char* adst = smem + buf*32768 + arow*128;
    #pragma unroll
    for (int j = 0; j < 4; ++j){
      floatx4 v0 = la[2*j], v1 = la[2*j+1];
      if (SCALED){ v0 *= rv; v1 *= rv; }
      short8 s;
      s[0]=(short)f2bf(v0[0]); s[1]=(short)f2bf(v0[1]); s[2]=(short)f2bf(v0[2]); s[3]=(short)f2bf(v0[3]);
      s[4]=(short)f2bf(v1[0]); s[5]=(short)f2bf(v1[1]); s[6]=(short)f2bf(v1[2]); s[7]=(short)f2bf(v1[3]);
      *(short8*)(adst + (((akh + j*8)*2) ^ ((arow & 7) << 4))) = s;
    }
    char* bdst = smem + 65536 + buf*16384 + brow*128;
    #pragma unroll
    for (int j = 0; j < 2; ++j){
      floatx4 v0 = lb[2*j], v1 = lb[2*j+1];
      short8 s;
      s[0]=(short)f2bf(v0[0]); s[1]=(short)f2bf(v0[1]); s[2]=(short)f2bf(v0[2]); s[3]=(short)f2bf(v0[3]);
      s[4]=(short)f2bf(v1[0]); s[5]=(short)f2bf(v1[1]); s[6]=(short)f2bf(v1[2]); s[7]=(short)f2bf(v1[3]);
      *(short8*)(bdst + (((bkh + j*8)*2) ^ ((brow & 7) << 4))) = s;
    }
  };

  auto compute = [&](int buf){
    const char* Ab = smem + buf*32768;
    const char* Bb = smem + 65536 + buf*16384;
    #pragma unroll
    for (int ks = 0; ks < 2; ++ks){
      const int kbyte = ks*64 + (lane >> 4)*16;
      short8 af[4], bf[4];
      #pragma unroll
      for (int mi = 0; mi < 4; ++mi) af[mi] = frag_ld64(Ab, wm*64 + mi*16 + (lane&15), kbyte);
      #pragma unroll
      for (int ni = 0; ni < 4; ++ni) bf[ni] = frag_ld64(Bb, wn*64 + ni*16 + (lane&15), kbyte);
      __builtin_amdgcn_s_setprio(1);
      #pragma unroll
      for (int mi = 0; mi < 4; ++mi)
        #pragma unroll
        for (int ni = 0; ni < 4; ++ni)
          acc[mi][ni] = __builtin_amdgcn_mfma_f32_16x16x32_bf16(af[mi], bf[ni], acc[mi][ni], 0,0,0);
      __builtin_amdgcn_s_setprio(0);
    }
  };

  issue(0);
  write_buf(0);
  __syncthreads();
  for (int s = 0; s < nsteps; ++s){
    const int cur = s & 1;
    if (s + 1 < nsteps) issue(s + 1);
    compute(cur);
    if (s + 1 < nsteps){
      write_buf(cur ^ 1);
      __syncthreads();
    }
  }

  #pragma unroll
  for (int ni = 0; ni < 4; ++ni){
    const int c = c0 + wn*64 + ni*16 + (lane & 15);
    const float bv = ATOMIC ? 0.0f : bias[c];
    #pragma unroll
    for (int mi = 0; mi < 4; ++mi){
      #pragma unroll
      for (int rg = 0; rg < 4; ++rg){
        const int t = t0 + wm*64 + mi*16 + (lane >> 4)*4 + rg;
        if (ATOMIC) atomicAdd(&out[(size_t)t*out_ld + c], acc[mi][ni][rg]);
        else        out[(size_t)t*out_ld + c] = acc[mi][ni][rg] + bv;
      }
    }
  }
}

extern "C" void kernel_launch(void* const* d_in, const int* in_sizes, int n_in,
                              void* d_out, int out_size, void* d_ws, size_t ws_size,
                              hipStream_t stream) {
  const float* r    = (const float*)d_in[0];   // [1024][512]
  const float* W1   = (const float*)d_in[1];   // [512][512]
  const float* b1   = (const float*)d_in[2];   // [512]
  const float* W2   = (const float*)d_in[3];   // [262144][512] == B[512 h][262144 K] flat
  const float* b2   = (const float*)d_in[4];   // [262144] == [512 h][512 n]
  const float* Wout = (const float*)d_in[5];   // [32000][512]
  const float* bout = (const float*)d_in[6];   // [32000]
  float* logits = (float*)d_out;               // [1024][32000]

  float* x_f32 = (float*)d_ws;                            // 2 MiB
  float* r_ol  = (float*)((char*)d_ws + 1024*512*4);      // 2 MiB

  // x = relu(r @ W1^T + b1)
  gemm_plain<0><<<16, 512, 0, stream>>>(r, W1, b1, x_f32, 512);
  // r_ol = r @ b2_2d^T  (bias part of einsum) — initializes the atomic target
  gemm_plain<1><<<16, 512, 0, stream>>>(r, b2, nullptr, r_ol, 512);
  // r_ol += (r*x) @ W2'^T : unified GEMM, K = 262144, 16 K-splits, 256 blocks
  gemm_pipe<1,1><<<256, 512, 0, stream>>>(x_f32, r, W2, nullptr, r_ol, 512, 4, 256, (size_t)262144);
  // logits = r_ol @ W_out^T + b_out : same template, K = 512
  gemm_pipe<0,0><<<1000, 512, 0, stream>>>(r_ol, nullptr, Wout, bout, logits, 32000, 250, 8, (size_t)512);
}

// Round 3
// 823.967 us; speedup vs baseline: 1.3608x; 1.3608x over previous
//
#include <hip/hip_runtime.h>
#include <hip/hip_bf16.h>

typedef __attribute__((ext_vector_type(8))) short short8;
typedef __attribute__((ext_vector_type(4))) short short4v;
typedef __attribute__((ext_vector_type(4))) float floatx4;

static __device__ __forceinline__ unsigned short f2bf(float f){
  union { float f; unsigned int u; } v; v.f = f;
  return (unsigned short)((v.u + 0x7FFFu + ((v.u >> 16) & 1u)) >> 16);  // RNE
}
static __device__ __forceinline__ float bf2f(unsigned short b){
  union { unsigned int u; float f; } v; v.u = ((unsigned int)b) << 16; return v.f;
}
static __device__ __forceinline__ short8 cvt8(floatx4 a, floatx4 b){
  short8 s;
  s[0]=(short)f2bf(a[0]); s[1]=(short)f2bf(a[1]); s[2]=(short)f2bf(a[2]); s[3]=(short)f2bf(a[3]);
  s[4]=(short)f2bf(b[0]); s[5]=(short)f2bf(b[1]); s[6]=(short)f2bf(b[2]); s[7]=(short)f2bf(b[3]);
  return s;
}
static __device__ __forceinline__ short4v cvt4(floatx4 a){
  short4v s; s[0]=(short)f2bf(a[0]); s[1]=(short)f2bf(a[1]); s[2]=(short)f2bf(a[2]); s[3]=(short)f2bf(a[3]);
  return s;
}
static __device__ __forceinline__ short8 scale8(short8 x, float rv){
  short8 o;
  #pragma unroll
  for (int i=0;i<8;++i) o[i] = (short)f2bf(bf2f((unsigned short)x[i]) * rv);
  return o;
}
// 128-byte LDS rows, XOR swizzle
static __device__ __forceinline__ short8 frag_ld64(const char* base, int row, int kbyte){
  return *(const short8*)(base + row*128 + (kbyte ^ ((row & 7) << 4)));
}

// ---------------- small-GEMM (K=512, 256-byte LDS rows) ----------------
template<int ROWS>
static __device__ __forceinline__ void stage_tile(char* ldsbase, const float* __restrict__ src,
                                                  int ld, int tid){
  #pragma unroll
  for (int w = 0; w < ROWS/32; ++w){
    int g = w*512 + tid;
    int row = g >> 4, k8 = g & 15;
    const float* p = src + (size_t)row*ld + k8*8;
    floatx4 v0 = *(const floatx4*)p;
    floatx4 v1 = *(const floatx4*)(p+4);
    *(short8*)(ldsbase + row*256 + ((k8*16) ^ ((row & 7) << 4))) = cvt8(v0, v1);
  }
}
static __device__ __forceinline__ short8 frag_ld(const char* ldsbase, int row, int kbyte){
  return *(const short8*)(ldsbase + row*256 + (kbyte ^ ((row & 7) << 4)));
}

// MODE 0: out(bf16) = relu(A@B^T + bias)  |  MODE 1: out(f32) = A@B^T
template<int MODE>
__global__ __launch_bounds__(512)
void gemm_plain(const float* __restrict__ Asrc, const float* __restrict__ Bsrc,
                const float* __restrict__ bias, void* __restrict__ out, int out_ld){
  __shared__ char smem[98304];
  char* At = smem;            // [256][128] bf16 swz
  char* Bt = smem + 65536;    // [128][128] bf16 swz
  const int tid  = threadIdx.x;
  const int lane = tid & 63, w = tid >> 6;
  const int wm = w & 3, wn = w >> 2;
  const int bid = blockIdx.x;
  const int t0 = (bid & 3) * 256;
  const int c0 = (bid >> 2) * 128;
  const int rbase = wm*64, cbase = wn*64;

  floatx4 acc[4][4];
  #pragma unroll
  for (int i=0;i<4;++i)
    #pragma unroll
    for (int j=0;j<4;++j) acc[i][j] = floatx4{0.f,0.f,0.f,0.f};

  for (int kb = 0; kb < 4; ++kb){
    __syncthreads();
    stage_tile<256>(At, Asrc + (size_t)t0*512 + kb*128, 512, tid);
    stage_tile<128>(Bt, Bsrc + (size_t)c0*512 + kb*128, 512, tid);
    __syncthreads();
    #pragma unroll
    for (int ks = 0; ks < 4; ++ks){
      const int kbyte = (ks*32 + (lane>>4)*8) * 2;
      short8 af[4], bf[4];
      #pragma unroll
      for (int mi=0; mi<4; ++mi) af[mi] = frag_ld(At, rbase + mi*16 + (lane&15), kbyte);
      #pragma unroll
      for (int ni=0; ni<4; ++ni) bf[ni] = frag_ld(Bt, cbase + ni*16 + (lane&15), kbyte);
      #pragma unroll
      for (int mi=0; mi<4; ++mi)
        #pragma unroll
        for (int ni=0; ni<4; ++ni)
          acc[mi][ni] = __builtin_amdgcn_mfma_f32_16x16x32_bf16(af[mi], bf[ni], acc[mi][ni], 0,0,0);
    }
  }
  #pragma unroll
  for (int mi=0; mi<4; ++mi){
    #pragma unroll
    for (int ni=0; ni<4; ++ni){
      #pragma unroll
      for (int rg=0; rg<4; ++rg){
        int t = t0 + rbase + mi*16 + (lane>>4)*4 + rg;
        int c = c0 + cbase + ni*16 + (lane&15);
        float v = acc[mi][ni][rg];
        if (MODE == 0){
          v += bias[c]; v = v > 0.f ? v : 0.f;
          ((unsigned short*)out)[(size_t)t*out_ld + c] = f2bf(v);
        } else {
          ((float*)out)[(size_t)t*out_ld + c] = v;
        }
      }
    }
  }
}

// ---------------- K2: r_ol += (r*x) @ W2'^T, K = 262144, full-row streaming ----------------
// grid 512 = m(4, fastest) x ht(4) x ns(32). Block: M=256 tokens, N=128 h, n-range 16, K'per n = 512.
// 128 sub-steps of BK=64; B batched 2 sub-steps (512 B/row in flight); A (x bf16) restaged per
// sub-step from L2 with per-row r-scale; lgkm-only barriers keep prefetches in flight.
__global__ __launch_bounds__(512, 2)
void k2_stream(const unsigned short* __restrict__ xbf, const float* __restrict__ r,
               const float* __restrict__ W2, float* __restrict__ r_ol){
  __shared__ char smem[131072];
  char* AB0 = smem;            // [256][64] bf16 swz
  char* AB1 = smem + 32768;
  const int tid = threadIdx.x;
  const int lane = tid & 63, w = tid >> 6;
  const int wm = w & 3, wn = w >> 2;     // 8 waves: 4M x 2N, wave tile 64x64
  const int bid = blockIdx.x;
  const int m  = bid & 3;
  const int ht = (bid >> 2) & 3;
  const int ns = bid >> 4;               // 0..31
  const int t0 = m*256, h0 = ht*128, n0 = ns*16;
  const int ar = tid >> 3, ac = tid & 7;     // A: 8 thr/row, 16B each
  const int br = tid >> 4, bc = tid & 15;    // B: 16 thr/row, 32B each

  floatx4 acc[4][4];
  #pragma unroll
  for (int i=0;i<4;++i)
    #pragma unroll
    for (int j=0;j<4;++j) acc[i][j] = floatx4{0.f,0.f,0.f,0.f};

  floatx4 lb0[8], lb1[8];
  short8 tA[4], tB[4];
  float rvA[4], rvB[4];

  auto BBp = [&](int p, int s) -> char* { return smem + 65536 + (p*2 + s)*16384; };

  auto issueB = [&](int hi, floatx4 (&lb)[8]){      // raw W2 tile pair for body hi
    int n = hi >> 2, q4 = hi & 3;
    const float* base = W2 + (size_t)h0*262144 + (size_t)(n0+n)*512 + q4*128 + bc*8;
    #pragma unroll
    for (int it = 0; it < 4; ++it){
      const float* p = base + (size_t)(it*32 + br)*262144;
      lb[it*2]   = *(const floatx4*)p;
      lb[it*2+1] = *(const floatx4*)(p+4);
    }
  };
  auto cvtB = [&](int hi, floatx4 (&lb)[8]){        // tiles(hi) -> BB[hi&1][0..1]
    char* dst = BBp(hi & 1, bc >> 3);
    #pragma unroll
    for (int it = 0; it < 4; ++it){
      int row = it*32 + br;
      *(short8*)(dst + row*128 + ((((bc & 7)*16)) ^ ((row & 7) << 4))) = cvt8(lb[it*2], lb[it*2+1]);
    }
  };
  auto issueA = [&](int hi, int sub, short8 (&t)[4], float (&rv)[4]){
    int n = hi >> 2, q4 = hi & 3;
    int kb = q4*128 + sub*64;
    #pragma unroll
    for (int it = 0; it < 4; ++it){
      int row = it*64 + ar;
      t[it]  = *(const short8*)(xbf + (size_t)(t0+row)*512 + kb + ac*8);
      rv[it] = r[(size_t)(t0+row)*512 + (n0+n)];
    }
  };
  auto cvtA = [&](short8 (&t)[4], float (&rv)[4], char* dst){
    #pragma unroll
    for (int it = 0; it < 4; ++it){
      int row = it*64 + ar;
      *(short8*)(dst + row*128 + ((ac*16) ^ ((row & 7) << 4))) = scale8(t[it], rv[it]);
    }
  };
  auto compute = [&](const char* Ab, const char* Bb){
    #pragma unroll
    for (int ks = 0; ks < 2; ++ks){
      const int kbyte = ks*64 + (lane >> 4)*16;
      short8 af[4], bf[4];
      #pragma unroll
      for (int mi = 0; mi < 4; ++mi) af[mi] = frag_ld64(Ab, wm*64 + mi*16 + (lane&15), kbyte);
      #pragma unroll
      for (int ni = 0; ni < 4; ++ni) bf[ni] = frag_ld64(Bb, wn*64 + ni*16 + (lane&15), kbyte);
      __builtin_amdgcn_s_setprio(1);
      #pragma unroll
      for (int mi = 0; mi < 4; ++mi)
        #pragma unroll
        for (int ni = 0; ni < 4; ++ni)
          acc[mi][ni] = __builtin_amdgcn_mfma_f32_16x16x32_bf16(af[mi], bf[ni], acc[mi][ni], 0,0,0);
      __builtin_amdgcn_s_setprio(0);
    }
  };

  // prologue
  issueB(0, lb0);
  issueB(1, lb1);
  issueA(0, 0, tB, rvB);
  issueA(0, 1, tA, rvA);
  cvtB(0, lb0);
  cvtA(tB, rvB, AB0);
  asm volatile("s_waitcnt lgkmcnt(0)" ::: "memory");
  __builtin_amdgcn_s_barrier();

#define K2_BODY(HI, LBE, LBO)                                         \
  {                                                                   \
    if ((HI) <= 61) issueB((HI)+2, LBE);                              \
    if ((HI) <= 62) cvtB((HI)+1, LBO);                                \
    cvtA(tA, rvA, AB1);                                               \
    if ((HI) <= 62) issueA((HI)+1, 0, tB, rvB);                       \
    compute(AB0, BBp((HI)&1, 0));                                     \
    asm volatile("s_waitcnt lgkmcnt(0)" ::: "memory");                \
    __builtin_amdgcn_s_barrier();                                     \
    if ((HI) <= 62) cvtA(tB, rvB, AB0);                               \
    if ((HI) <= 62) issueA((HI)+1, 1, tA, rvA);                       \
    compute(AB1, BBp((HI)&1, 1));                                     \
    asm volatile("s_waitcnt lgkmcnt(0)" ::: "memory");                \
    __builtin_amdgcn_s_barrier();                                     \
  }

  for (int h2 = 0; h2 < 32; ++h2){
    K2_BODY(2*h2,     lb0, lb1);
    K2_BODY(2*h2 + 1, lb1, lb0);
  }
#undef K2_BODY

  #pragma unroll
  for (int ni = 0; ni < 4; ++ni){
    const int h = h0 + wn*64 + ni*16 + (lane & 15);
    #pragma unroll
    for (int mi = 0; mi < 4; ++mi){
      #pragma unroll
      for (int rg = 0; rg < 4; ++rg){
        const int t = t0 + wm*64 + mi*16 + (lane >> 4)*4 + rg;
        atomicAdd(&r_ol[(size_t)t*512 + h], acc[mi][ni][rg]);
      }
    }
  }
}

// ---------------- K3: logits = r_ol @ Wout^T + bout (K=512) ----------------
__global__ __launch_bounds__(512, 2)
void gemm_out(const float* __restrict__ Asrc, const float* __restrict__ Bsrc,
              const float* __restrict__ bias, float* __restrict__ out){
  __shared__ char smem[98304];   // A dbuf 2x[256][64] swz, B dbuf 2x[128][64] swz
  const int tid  = threadIdx.x;
  const int lane = tid & 63, w = tid >> 6;
  const int wm = w & 3, wn = w >> 2;
  const int bid = blockIdx.x;
  const int t0 = (bid & 3) * 256;
  const int c0 = (bid >> 2) * 128;

  floatx4 acc[4][4];
  #pragma unroll
  for (int i=0;i<4;++i)
    #pragma unroll
    for (int j=0;j<4;++j) acc[i][j] = floatx4{0.f,0.f,0.f,0.f};

  floatx4 la[8], lb[4];
  const int r16 = tid >> 4, c4 = tid & 15;

  auto issue = [&](int s){
    const int K0 = s*64;
    #pragma unroll
    for (int it=0; it<8; ++it){
      int row = it*32 + r16;
      la[it] = *(const floatx4*)(Asrc + (size_t)(t0+row)*512 + K0 + c4*4);
    }
    #pragma unroll
    for (int it=0; it<4; ++it){
      int row = it*32 + r16;
      lb[it] = *(const floatx4*)(Bsrc + (size_t)(c0+row)*512 + K0 + c4*4);
    }
  };
  auto write_buf = [&](int buf){
    char* ad = smem + buf*32768;
    #pragma unroll
    for (int it=0; it<8; ++it){
      int row = it*32 + r16;
      *(short4v*)(ad + row*128 + ((c4*8) ^ ((row & 7) << 4))) = cvt4(la[it]);
    }
    char* bd = smem + 65536 + buf*16384;
    #pragma unroll
    for (int it=0; it<4; ++it){
      int row = it*32 + r16;
      *(short4v*)(bd + row*128 + ((c4*8) ^ ((row & 7) << 4))) = cvt4(lb[it]);
    }
  };
  auto compute = [&](int buf){
    const char* Ab = smem + buf*32768;
    const char* Bb = smem + 65536 + buf*16384;
    #pragma unroll
    for (int ks = 0; ks < 2; ++ks){
      const int kbyte = ks*64 + (lane >> 4)*16;
      short8 af[4], bf[4];
      #pragma unroll
      for (int mi = 0; mi < 4; ++mi) af[mi] = frag_ld64(Ab, wm*64 + mi*16 + (lane&15), kbyte);
      #pragma unroll
      for (int ni = 0; ni < 4; ++ni) bf[ni] = frag_ld64(Bb, wn*64 + ni*16 + (lane&15), kbyte);
      __builtin_amdgcn_s_setprio(1);
      #pragma unroll
      for (int mi = 0; mi < 4; ++mi)
        #pragma unroll
        for (int ni = 0; ni < 4; ++ni)
          acc[mi][ni] = __builtin_amdgcn_mfma_f32_16x16x32_bf16(af[mi], bf[ni], acc[mi][ni], 0,0,0);
      __builtin_amdgcn_s_setprio(0);
    }
  };

  issue(0);
  write_buf(0);
  __syncthreads();
  for (int s = 0; s < 8; ++s){
    const int cur = s & 1;
    if (s < 7) issue(s + 1);
    compute(cur);
    if (s < 7){
      write_buf(cur ^ 1);
      __syncthreads();
    }
  }

  #pragma unroll
  for (int ni = 0; ni < 4; ++ni){
    const int c = c0 + wn*64 + ni*16 + (lane & 15);
    const float bv = bias[c];
    #pragma unroll
    for (int mi = 0; mi < 4; ++mi){
      #pragma unroll
      for (int rg = 0; rg < 4; ++rg){
        const int t = t0 + wm*64 + mi*16 + (lane >> 4)*4 + rg;
        out[(size_t)t*32000 + c] = acc[mi][ni][rg] + bv;
      }
    }
  }
}

extern "C" void kernel_launch(void* const* d_in, const int* in_sizes, int n_in,
                              void* d_out, int out_size, void* d_ws, size_t ws_size,
                              hipStream_t stream) {
  const float* r    = (const float*)d_in[0];   // [1024][512]
  const float* W1   = (const float*)d_in[1];   // [512][512]
  const float* b1   = (const float*)d_in[2];   // [512]
  const float* W2   = (const float*)d_in[3];   // [262144][512] == B'[512 h][262144 K'] flat
  const float* b2   = (const float*)d_in[4];   // [262144] == [512 h][512 n]
  const float* Wout = (const float*)d_in[5];   // [32000][512]
  const float* bout = (const float*)d_in[6];   // [32000]
  float* logits = (float*)d_out;               // [1024][32000]

  unsigned short* x_bf = (unsigned short*)d_ws;                 // 1 MiB bf16
  float* r_ol = (float*)((char*)d_ws + 1024*512*2);             // 2 MiB f32

  // x = relu(r @ W1^T + b1) -> bf16
  gemm_plain<0><<<16, 512, 0, stream>>>(r, W1, b1, x_bf, 512);
  // r_ol = r @ b2_2d^T (bias part of einsum) -> init atomic target
  gemm_plain<1><<<16, 512, 0, stream>>>(r, b2, nullptr, r_ol, 512);
  // r_ol += (r*x) @ W2'^T
  k2_stream<<<512, 512, 0, stream>>>(x_bf, r, W2, r_ol);
  // logits = r_ol @ Wout^T + bout
  gemm_out<<<1000, 512, 0, stream>>>(r_ol, Wout, bout, logits);
}

// Round 4
// 516.978 us; speedup vs baseline: 2.1689x; 1.5938x over previous
//
#include <hip/hip_runtime.h>
#include <hip/hip_bf16.h>

typedef __attribute__((ext_vector_type(8))) short short8;
typedef __attribute__((ext_vector_type(4))) short short4v;
typedef __attribute__((ext_vector_type(4))) float floatx4;

static __device__ __forceinline__ unsigned short f2bf(float f){
  union { float f; unsigned int u; } v; v.f = f;
  return (unsigned short)((v.u + 0x7FFFu + ((v.u >> 16) & 1u)) >> 16);  // RNE
}
static __device__ __forceinline__ short8 cvt8(floatx4 a, floatx4 b){
  short8 s;
  s[0]=(short)f2bf(a[0]); s[1]=(short)f2bf(a[1]); s[2]=(short)f2bf(a[2]); s[3]=(short)f2bf(a[3]);
  s[4]=(short)f2bf(b[0]); s[5]=(short)f2bf(b[1]); s[6]=(short)f2bf(b[2]); s[7]=(short)f2bf(b[3]);
  return s;
}
// packed cvt via compiler (v_cvt_pk_bf16_f32)
static __device__ __forceinline__ short8 cvt8_pk(floatx4 a, floatx4 b){
  union { __hip_bfloat162 h[4]; short8 s; } u;
  u.h[0] = __float22bfloat162_rn(float2{a[0], a[1]});
  u.h[1] = __float22bfloat162_rn(float2{a[2], a[3]});
  u.h[2] = __float22bfloat162_rn(float2{b[0], b[1]});
  u.h[3] = __float22bfloat162_rn(float2{b[2], b[3]});
  return u.s;
}
static __device__ __forceinline__ short4v cvt4(floatx4 a){
  union { __hip_bfloat162 h[2]; short4v s; } u;
  u.h[0] = __float22bfloat162_rn(float2{a[0], a[1]});
  u.h[1] = __float22bfloat162_rn(float2{a[2], a[3]});
  return u.s;
}
// 256-byte LDS rows, XOR swizzle on bytes 4..6
static __device__ __forceinline__ short8 frag_ld(const char* ldsbase, int row, int kbyte){
  return *(const short8*)(ldsbase + row*256 + (kbyte ^ ((row & 7) << 4)));
}
// 128-byte LDS rows
static __device__ __forceinline__ short8 frag_ld64(const char* base, int row, int kbyte){
  return *(const short8*)(base + row*128 + (kbyte ^ ((row & 7) << 4)));
}

// ---------------- small GEMMs (K=512) ----------------
template<int ROWS>
static __device__ __forceinline__ void stage_tile(char* ldsbase, const float* __restrict__ src,
                                                  int ld, int tid){
  #pragma unroll
  for (int w = 0; w < ROWS/32; ++w){
    int g = w*512 + tid;
    int row = g >> 4, k8 = g & 15;
    const float* p = src + (size_t)row*ld + k8*8;
    floatx4 v0 = *(const floatx4*)p;
    floatx4 v1 = *(const floatx4*)(p+4);
    *(short8*)(ldsbase + row*256 + ((k8*16) ^ ((row & 7) << 4))) = cvt8_pk(v0, v1);
  }
}

// MODE 0: out(bf16) = relu(A@B^T + bias)  |  MODE 1: out(f32) = A@B^T
template<int MODE>
__global__ __launch_bounds__(512)
void gemm_plain(const float* __restrict__ Asrc, const float* __restrict__ Bsrc,
                const float* __restrict__ bias, void* __restrict__ out, int out_ld){
  __shared__ char smem[98304];
  char* At = smem;            // [256][128] bf16 swz
  char* Bt = smem + 65536;    // [128][128] bf16 swz
  const int tid  = threadIdx.x;
  const int lane = tid & 63, w = tid >> 6;
  const int wm = w & 3, wn = w >> 2;
  const int bid = blockIdx.x;
  const int t0 = (bid & 3) * 256;
  const int c0 = (bid >> 2) * 128;
  const int rbase = wm*64, cbase = wn*64;

  floatx4 acc[4][4];
  #pragma unroll
  for (int i=0;i<4;++i)
    #pragma unroll
    for (int j=0;j<4;++j) acc[i][j] = floatx4{0.f,0.f,0.f,0.f};

  for (int kb = 0; kb < 4; ++kb){
    __syncthreads();
    stage_tile<256>(At, Asrc + (size_t)t0*512 + kb*128, 512, tid);
    stage_tile<128>(Bt, Bsrc + (size_t)c0*512 + kb*128, 512, tid);
    __syncthreads();
    #pragma unroll
    for (int ks = 0; ks < 4; ++ks){
      const int kbyte = (ks*32 + (lane>>4)*8) * 2;
      short8 af[4], bfr[4];
      #pragma unroll
      for (int mi=0; mi<4; ++mi) af[mi] = frag_ld(At, rbase + mi*16 + (lane&15), kbyte);
      #pragma unroll
      for (int ni=0; ni<4; ++ni) bfr[ni] = frag_ld(Bt, cbase + ni*16 + (lane&15), kbyte);
      #pragma unroll
      for (int mi=0; mi<4; ++mi)
        #pragma unroll
        for (int ni=0; ni<4; ++ni)
          acc[mi][ni] = __builtin_amdgcn_mfma_f32_16x16x32_bf16(af[mi], bfr[ni], acc[mi][ni], 0,0,0);
    }
  }
  #pragma unroll
  for (int mi=0; mi<4; ++mi){
    #pragma unroll
    for (int ni=0; ni<4; ++ni){
      #pragma unroll
      for (int rg=0; rg<4; ++rg){
        int t = t0 + rbase + mi*16 + (lane>>4)*4 + rg;
        int c = c0 + cbase + ni*16 + (lane&15);
        float v = acc[mi][ni][rg];
        if (MODE == 0){
          v += bias[c]; v = v > 0.f ? v : 0.f;
          ((unsigned short*)out)[(size_t)t*out_ld + c] = f2bf(v);
        } else {
          ((float*)out)[(size_t)t*out_ld + c] = v;
        }
      }
    }
  }
}

// ---------------- K2: r_ol += einsum, fold-on-output structure ----------------
// Block: M=256 tokens, N=128 h, 16 n-values, K'=512 per n. 64 bodies of (kb,n); BK=128.
// bid mapping groups the 4 m-sharers of each W2 region on one XCD (bid mod 8).
__global__ __launch_bounds__(512, 2)
void k2_fold(const unsigned short* __restrict__ xbf, const float* __restrict__ r,
             const float* __restrict__ W2, float* __restrict__ r_ol){
  __shared__ char smem[148480];   // A[256][256B] @0; B dbuf 2x[128][256B] @65536; RT @131072
  float* RT = (float*)(smem + 131072);   // [256][17] f32
  const int tid  = threadIdx.x;
  const int lane = tid & 63, w = tid >> 6;
  const int wm = w & 3, wn = w >> 2;       // 8 waves: 4M x 2N, wave tile 64x64
  const int bid = blockIdx.x;
  const int xr = bid & 7, slot = bid >> 3;
  const int m  = slot & 3;
  const int g  = (slot >> 2) * 8 + xr;     // group 0..127
  const int ht = g & 3, ns = g >> 2;
  const int t0 = m*256, h0 = ht*128, n0 = ns*16;

  // stage r-scales [256 rows][16 n]
  #pragma unroll
  for (int i = 0; i < 8; ++i){
    int e = i*512 + tid; int row = e >> 4, c = e & 15;
    RT[row*17 + c] = r[(size_t)(t0+row)*512 + n0 + c];
  }

  const int br = tid >> 2, bseg = tid & 3;   // B stage: 4 thr/row, 128 B contiguous each
  const int arow = tid >> 1, ahalf = tid & 1; // A stage: 2 thr/row, 128 B each

  floatx4 acc[4][4];
  #pragma unroll
  for (int i=0;i<4;++i)
    #pragma unroll
    for (int j=0;j<4;++j) acc[i][j] = floatx4{0.f,0.f,0.f,0.f};

  floatx4 lb[8];

  auto issueB = [&](int n, int kb){
    const float* p = W2 + (size_t)(h0+br)*262144 + (size_t)(n0+n)*512 + kb*128 + bseg*32;
    #pragma unroll
    for (int i = 0; i < 8; ++i) lb[i] = *(const floatx4*)(p + i*4);
  };
  auto cvtB = [&](char* Bb){
    char* dst = Bb + br*256;
    #pragma unroll
    for (int j = 0; j < 4; ++j)
      *(short8*)(dst + ((bseg*64 + j*16) ^ ((br & 7) << 4))) = cvt8_pk(lb[2*j], lb[2*j+1]);
  };
  auto stageA = [&](int kb){
    const unsigned short* src = xbf + (size_t)(t0+arow)*512 + kb*128 + ahalf*64;
    char* dst = smem + arow*256;
    #pragma unroll
    for (int j = 0; j < 8; ++j){
      short8 v = *(const short8*)(src + j*8);
      *(short8*)(dst + ((ahalf*128 + j*16) ^ ((arow & 7) << 4))) = v;
    }
  };
  auto compute_fold = [&](const char* Bb, int n){
    floatx4 ct[4][4];
    #pragma unroll
    for (int ks = 0; ks < 4; ++ks){
      const int kbyte = (ks*32 + (lane>>4)*8) * 2;
      short8 af[4], bfr[4];
      #pragma unroll
      for (int mi=0; mi<4; ++mi) af[mi] = frag_ld(smem, wm*64 + mi*16 + (lane&15), kbyte);
      #pragma unroll
      for (int ni=0; ni<4; ++ni) bfr[ni] = frag_ld(Bb, wn*64 + ni*16 + (lane&15), kbyte);
      __builtin_amdgcn_s_setprio(1);
      #pragma unroll
      for (int mi=0; mi<4; ++mi)
        #pragma unroll
        for (int ni=0; ni<4; ++ni)
          ct[mi][ni] = __builtin_amdgcn_mfma_f32_16x16x32_bf16(
              af[mi], bfr[ni], (ks==0) ? floatx4{0.f,0.f,0.f,0.f} : ct[mi][ni], 0,0,0);
      __builtin_amdgcn_s_setprio(0);
    }
    #pragma unroll
    for (int mi=0; mi<4; ++mi){
      const int rrow = wm*64 + mi*16 + (lane>>4)*4;
      float rv0 = RT[(rrow+0)*17 + n];
      float rv1 = RT[(rrow+1)*17 + n];
      float rv2 = RT[(rrow+2)*17 + n];
      float rv3 = RT[(rrow+3)*17 + n];
      #pragma unroll
      for (int ni=0; ni<4; ++ni){
        acc[mi][ni][0] += rv0 * ct[mi][ni][0];
        acc[mi][ni][1] += rv1 * ct[mi][ni][1];
        acc[mi][ni][2] += rv2 * ct[mi][ni][2];
        acc[mi][ni][3] += rv3 * ct[mi][ni][3];
      }
    }
  };

  // prologue
  stageA(0);
  issueB(0, 0);
  cvtB(smem + 65536);
  __syncthreads();

  int cur = 0;
  for (int kb = 0; kb < 4; ++kb){
    for (int n = 0; n < 16; ++n){
      const int bi = kb*16 + n;
      const bool hn = (bi < 63);
      const int nn  = (n == 15) ? 0 : n + 1;
      const int nkb = (n == 15) ? kb + 1 : kb;
      if (hn) issueB(nn, nkb);
      compute_fold(smem + 65536 + cur*32768, n);
      if (hn) cvtB(smem + 65536 + (cur^1)*32768);
      __syncthreads();
      cur ^= 1;
    }
    if (kb < 3){
      stageA(kb + 1);
      __syncthreads();
    }
  }

  #pragma unroll
  for (int ni = 0; ni < 4; ++ni){
    const int h = h0 + wn*64 + ni*16 + (lane & 15);
    #pragma unroll
    for (int mi = 0; mi < 4; ++mi){
      #pragma unroll
      for (int rg = 0; rg < 4; ++rg){
        const int t = t0 + wm*64 + mi*16 + (lane >> 4)*4 + rg;
        atomicAdd(&r_ol[(size_t)t*512 + h], acc[mi][ni][rg]);
      }
    }
  }
}

// ---------------- K3: logits = r_ol @ Wout^T + bout (K=512) ----------------
__global__ __launch_bounds__(512, 2)
void gemm_out(const float* __restrict__ Asrc, const float* __restrict__ Bsrc,
              const float* __restrict__ bias, float* __restrict__ out){
  __shared__ char smem[98304];   // A dbuf 2x[256][128B] swz, B dbuf 2x[128][128B] swz
  const int tid  = threadIdx.x;
  const int lane = tid & 63, w = tid >> 6;
  const int wm = w & 3, wn = w >> 2;
  const int bid = blockIdx.x;
  const int t0 = (bid & 3) * 256;
  const int c0 = (bid >> 2) * 128;

  floatx4 acc[4][4];
  #pragma unroll
  for (int i=0;i<4;++i)
    #pragma unroll
    for (int j=0;j<4;++j) acc[i][j] = floatx4{0.f,0.f,0.f,0.f};

  floatx4 la[8], lb[4];
  const int r16 = tid >> 4, c4 = tid & 15;

  auto issue = [&](int s){
    const int K0 = s*64;
    #pragma unroll
    for (int it=0; it<8; ++it){
      int row = it*32 + r16;
      la[it] = *(const floatx4*)(Asrc + (size_t)(t0+row)*512 + K0 + c4*4);
    }
    #pragma unroll
    for (int it=0; it<4; ++it){
      int row = it*32 + r16;
      lb[it] = *(const floatx4*)(Bsrc + (size_t)(c0+row)*512 + K0 + c4*4);
    }
  };
  auto write_buf = [&](int buf){
    char* ad = smem + buf*32768;
    #pragma unroll
    for (int it=0; it<8; ++it){
      int row = it*32 + r16;
      *(short4v*)(ad + row*128 + ((c4*8) ^ ((row & 7) << 4))) = cvt4(la[it]);
    }
    char* bd = smem + 65536 + buf*16384;
    #pragma unroll
    for (int it=0; it<4; ++it){
      int row = it*32 + r16;
      *(short4v*)(bd + row*128 + ((c4*8) ^ ((row & 7) << 4))) = cvt4(lb[it]);
    }
  };
  auto compute = [&](int buf){
    const char* Ab = smem + buf*32768;
    const char* Bb = smem + 65536 + buf*16384;
    #pragma unroll
    for (int ks = 0; ks < 2; ++ks){
      const int kbyte = ks*64 + (lane >> 4)*16;
      short8 af[4], bfr[4];
      #pragma unroll
      for (int mi = 0; mi < 4; ++mi) af[mi] = frag_ld64(Ab, wm*64 + mi*16 + (lane&15), kbyte);
      #pragma unroll
      for (int ni = 0; ni < 4; ++ni) bfr[ni] = frag_ld64(Bb, wn*64 + ni*16 + (lane&15), kbyte);
      __builtin_amdgcn_s_setprio(1);
      #pragma unroll
      for (int mi = 0; mi < 4; ++mi)
        #pragma unroll
        for (int ni = 0; ni < 4; ++ni)
          acc[mi][ni] = __builtin_amdgcn_mfma_f32_16x16x32_bf16(af[mi], bfr[ni], acc[mi][ni], 0,0,0);
      __builtin_amdgcn_s_setprio(0);
    }
  };

  issue(0);
  write_buf(0);
  __syncthreads();
  for (int s = 0; s < 8; ++s){
    const int cur = s & 1;
    if (s < 7) issue(s + 1);
    compute(cur);
    if (s < 7){
      write_buf(cur ^ 1);
      __syncthreads();
    }
  }

  #pragma unroll
  for (int ni = 0; ni < 4; ++ni){
    const int c = c0 + wn*64 + ni*16 + (lane & 15);
    const float bv = bias[c];
    #pragma unroll
    for (int mi = 0; mi < 4; ++mi){
      #pragma unroll
      for (int rg = 0; rg < 4; ++rg){
        const int t = t0 + wm*64 + mi*16 + (lane >> 4)*4 + rg;
        out[(size_t)t*32000 + c] = acc[mi][ni][rg] + bv;
      }
    }
  }
}

extern "C" void kernel_launch(void* const* d_in, const int* in_sizes, int n_in,
                              void* d_out, int out_size, void* d_ws, size_t ws_size,
                              hipStream_t stream) {
  const float* r    = (const float*)d_in[0];   // [1024][512]
  const float* W1   = (const float*)d_in[1];   // [512][512]
  const float* b1   = (const float*)d_in[2];   // [512]
  const float* W2   = (const float*)d_in[3];   // [262144][512]
  const float* b2   = (const float*)d_in[4];   // [262144] == [512 h][512 n]
  const float* Wout = (const float*)d_in[5];   // [32000][512]
  const float* bout = (const float*)d_in[6];   // [32000]
  float* logits = (float*)d_out;               // [1024][32000]

  unsigned short* x_bf = (unsigned short*)d_ws;                 // 1 MiB bf16
  float* r_ol = (float*)((char*)d_ws + 1024*512*2);             // 2 MiB f32

  // x = relu(r @ W1^T + b1) -> bf16
  gemm_plain<0><<<16, 512, 0, stream>>>(r, W1, b1, x_bf, 512);
  // r_ol = r @ b2_2d^T (bias part of einsum) -> init atomic target
  gemm_plain<1><<<16, 512, 0, stream>>>(r, b2, nullptr, r_ol, 512);
  // r_ol += fold-structured big GEMM
  k2_fold<<<512, 512, 0, stream>>>(x_bf, r, W2, r_ol);
  // logits = r_ol @ Wout^T + bout
  gemm_out<<<1000, 512, 0, stream>>>(r_ol, Wout, bout, logits);
}